// Round 9
// baseline (103.859 us; speedup 1.0000x reference)
//
#include <hip/hip_runtime.h>

typedef __bf16 bf16;
typedef float f32x4 __attribute__((ext_vector_type(4)));
typedef bf16 bf16x4 __attribute__((ext_vector_type(4)));
typedef bf16 bf16x8 __attribute__((ext_vector_type(8)));

#define MFMA16(a, b, c) __builtin_amdgcn_mfma_f32_16x16x32_bf16((a), (b), (c), 0, 0, 0)

__device__ __forceinline__ f32x4 zero4() {
    f32x4 z; z[0] = 0.f; z[1] = 0.f; z[2] = 0.f; z[3] = 0.f; return z;
}
// async global -> LDS, 16B/lane. LDS dest = wave-uniform base + lane*16.
__device__ __forceinline__ void gl_lds16(const bf16* g, bf16* l) {
    __builtin_amdgcn_global_load_lds(
        (const __attribute__((address_space(1))) void*)g,
        (__attribute__((address_space(3))) void*)l, 16, 0, 0);
}

// ---------------- prep: f32 -> bf16 elementwise ----------------
__global__ __launch_bounds__(256) void conv_k(const float* __restrict__ src,
                                              bf16* __restrict__ dst, int n)
{
    const int i = (blockIdx.x * 256 + threadIdx.x) * 8;
    if (i >= n) return;
    const float4 a = *(const float4*)(src + i);
    const float4 b = *(const float4*)(src + i + 4);
    bf16x8 o;
    o[0] = (bf16)a.x; o[1] = (bf16)a.y; o[2] = (bf16)a.z; o[3] = (bf16)a.w;
    o[4] = (bf16)b.x; o[5] = (bf16)b.y; o[6] = (bf16)b.z; o[7] = (bf16)b.w;
    *(bf16x8*)(dst + i) = o;
}

// ---------------- prep: transpose+convert w [K][N] f32 -> wT [N][K] bf16 ----------------
__global__ __launch_bounds__(256) void transp_k(const float* __restrict__ src,
                                                bf16* __restrict__ dst, int K, int N)
{
    __shared__ bf16 Ls[64][72];
    const int tid = threadIdx.x;
    const int k0 = blockIdx.y << 6;
    const int n0 = blockIdx.x << 6;
    #pragma unroll
    for (int it = 0; it < 4; ++it) {
        const int lin = (it << 10) + (tid << 2);
        const int r = lin >> 6, c = lin & 63;
        const float4 v = *(const float4*)(src + (size_t)(k0 + r) * N + n0 + c);
        bf16x4 o; o[0] = (bf16)v.x; o[1] = (bf16)v.y; o[2] = (bf16)v.z; o[3] = (bf16)v.w;
        *(bf16x4*)&Ls[r][c] = o;
    }
    __syncthreads();
    #pragma unroll
    for (int it = 0; it < 2; ++it) {
        const int lin = (it << 11) + (tid << 3);
        const int nn = lin >> 6, kk = lin & 63;
        bf16x8 o;
        #pragma unroll
        for (int j = 0; j < 8; ++j) o[j] = Ls[kk + j][nn];
        *(bf16x8*)(dst + (size_t)(n0 + nn) * K + k0 + kk) = o;
    }
}

// ---------------- bf16 GEMM, B^T input, depth-2 counted-vmcnt pipeline, BK=32 ----------------
// MODE 0: BM=256 BN=128 (wave tile 128x64, MF=8: 12 ds_read_b128 feed 32 MFMA ->
//         MFMA-limited, not LDS-read-limited). Scatter q/k packed [bh][t][d] +
//         v transposed+t-permuted [bh][d][t'] via LDS-pack epilogue.
// MODE 1: BM=128 BN=64, f32 out + bias, direct stores.
template <int MODE>
__global__ __launch_bounds__(256)
void gemm_bt(const bf16* __restrict__ A, const bf16* __restrict__ Bt,
             const float* __restrict__ bias,
             bf16* __restrict__ qw, bf16* __restrict__ kw, bf16* __restrict__ vw,
             float* __restrict__ outf, int M, int N, int K)
{
    constexpr int BK = 32;
    constexpr int BM = (MODE == 0) ? 256 : 128;
    constexpr int BN = (MODE == 0) ? 128 : 64;
    constexpr int MF = BM / 32;                  // 8 or 4... per-wave 16-row frags
    constexpr int NF = 4;
    constexpr int AE = BM * BK;
    constexpr int BE = BN * BK;
    constexpr int AI = BM / 64;                  // A staging instrs per wave
    constexpr int BI = BN / 64;                  // B staging instrs per wave
    constexpr int LPI = AI + BI;                 // 6 (MODE0) / 3 (MODE1)
    constexpr int WMF = (MODE == 0) ? 8 : 2;     // per-wave M frags

    __shared__ __align__(16) bf16 smem[3 * (AE + BE)];
    bf16* const Asb = smem;
    bf16* const Bsb = smem + 3 * AE;

    const int tid  = threadIdx.x;
    const int lane = tid & 63;
    const int wid  = tid >> 6;
    const int l16  = lane & 15;
    const int g    = lane >> 4;
    const int wrb  = (MODE == 0) ? ((wid >> 1) << 7) : (wid << 5);
    const int wcb  = (MODE == 0) ? ((wid & 1) << 6) : 0;
    const int m0   = blockIdx.y * BM;
    const int n0   = blockIdx.x * BN;

    // staging: 16 rows x 64B per instr; source chunk XOR-preswizzled by (row>>1)&3
    const int srow = lane >> 2;
    const int schk = lane & 3;
    const bf16* pa[AI];
    const bf16* pb[BI];
    int dA[AI], dB[BI];
    #pragma unroll
    for (int i = 0; i < AI; ++i) {
        const int r = wid * (BM / 4) + (i << 4);
        pa[i] = A + (size_t)(m0 + r + srow) * K + ((schk ^ (((r + srow) >> 1) & 3)) << 3);
        dA[i] = r * BK;
    }
    #pragma unroll
    for (int i = 0; i < BI; ++i) {
        const int r = wid * (BN / 4) + (i << 4);
        pb[i] = Bt + (size_t)(n0 + r + srow) * K + ((schk ^ (((r + srow) >> 1) & 3)) << 3);
        dB[i] = r * BK;
    }

    auto issue = [&](bf16* ab, bf16* bb) {
        #pragma unroll
        for (int i = 0; i < AI; ++i) gl_lds16(pa[i], ab + dA[i]);
        #pragma unroll
        for (int i = 0; i < BI; ++i) gl_lds16(pb[i], bb + dB[i]);
        #pragma unroll
        for (int i = 0; i < AI; ++i) pa[i] += BK;
        #pragma unroll
        for (int i = 0; i < BI; ++i) pb[i] += BK;
    };

    // fragment read offsets (elems), swizzle-matched
    int offA[WMF], offB[NF];
    #pragma unroll
    for (int mf = 0; mf < WMF; ++mf) {
        const int r = wrb + (mf << 4) + l16;
        offA[mf] = r * BK + ((g ^ ((r >> 1) & 3)) << 3);
    }
    #pragma unroll
    for (int nf = 0; nf < NF; ++nf) {
        const int r = wcb + (nf << 4) + l16;
        offB[nf] = r * BK + ((g ^ ((r >> 1) & 3)) << 3);
    }

    f32x4 acc[WMF][NF];
    #pragma unroll
    for (int i = 0; i < WMF; ++i)
        #pragma unroll
        for (int j = 0; j < NF; ++j) acc[i][j] = zero4();

    const int nk = K >> 5;
    issue(Asb, Bsb);
    issue(Asb + AE, Bsb + BE);

    for (int kt = 0; kt < nk; ++kt) {
        if (kt == nk - 1) {
            asm volatile("s_waitcnt vmcnt(0)" ::: "memory");
        } else {
            if constexpr (LPI == 6) asm volatile("s_waitcnt vmcnt(6)" ::: "memory");
            else                    asm volatile("s_waitcnt vmcnt(3)" ::: "memory");
        }
        __builtin_amdgcn_s_barrier();            // tile kt staged for all waves
        const int nxt = kt + 2;
        if (nxt < nk) {
            const int s = nxt - (nxt / 3) * 3;
            issue(Asb + s * AE, Bsb + s * BE);
        }
        const int c = kt - (kt / 3) * 3;
        const bf16* ac = Asb + c * AE;
        const bf16* bc = Bsb + c * BE;
        bf16x8 af[WMF], bfr[NF];
        #pragma unroll
        for (int mf = 0; mf < WMF; ++mf) af[mf] = *(const bf16x8*)&ac[offA[mf]];
        #pragma unroll
        for (int nf = 0; nf < NF; ++nf) bfr[nf] = *(const bf16x8*)&bc[offB[nf]];
        __builtin_amdgcn_s_setprio(1);
        #pragma unroll
        for (int mf = 0; mf < WMF; ++mf)
            #pragma unroll
            for (int nf = 0; nf < NF; ++nf)
                acc[mf][nf] = MFMA16(af[mf], bfr[nf], acc[mf][nf]);
        __builtin_amdgcn_s_setprio(0);
    }
    __syncthreads();                             // reads done before smem reuse

    if (MODE == 0) {
        // ---- LDS-pack epilogue: 256x128 tile reusing smem (64KB of 72KB) ----
        bf16* const Es = smem;
        const int bq  = m0 >> 10;
        const int tb  = m0 & 1023;
        const int hh0 = (n0 & 1023) >> 6;
        const bool isV = (n0 >= 2048);
        if (isV) {
            // Es layout [nn(128)][m'(256)], m' = PV-kmap permute of m
            #pragma unroll
            for (int mf = 0; mf < WMF; ++mf)
                #pragma unroll
                for (int nf = 0; nf < NF; ++nf) {
                    const int nn = wcb + (nf << 4) + l16;
                    const float bs = bias[n0 + nn];
                    bf16x4 p;
                    #pragma unroll
                    for (int j = 0; j < 4; ++j) p[j] = (bf16)(acc[mf][nf][j] + bs);
                    const int m = wrb + (mf << 4) + (g << 2);
                    const int pp = ((m >> 5) << 5) + (((m >> 2) & 3) << 3) + (((m >> 4) & 1) << 2);
                    *(bf16x4*)&Es[nn * 256 + pp] = p;
                }
        } else {
            // Es layout [m(256)][nn(128)]
            #pragma unroll
            for (int mf = 0; mf < WMF; ++mf)
                #pragma unroll
                for (int nf = 0; nf < NF; ++nf) {
                    const int nn = wcb + (nf << 4) + l16;
                    const float bs = bias[n0 + nn];
                    #pragma unroll
                    for (int j = 0; j < 4; ++j) {
                        const int mm = wrb + (mf << 4) + (g << 2) + j;
                        Es[mm * 128 + nn] = (bf16)(acc[mf][nf][j] + bs);
                    }
                }
        }
        __syncthreads();
        #pragma unroll
        for (int it = 0; it < 16; ++it) {
            const int elem = ((it << 8) + tid) << 3;
            if (isV) {
                const int nn = elem >> 8, mp = elem & 255;
                const bf16x8 v = *(const bf16x8*)&Es[elem];
                const int dd = nn & 63, hh = hh0 + (nn >> 6);
                *(bf16x8*)(vw + ((size_t)((bq << 4) + hh) << 16) + ((size_t)dd << 10)
                           + tb + mp) = v;
            } else {
                const int mm = elem >> 7, cc = elem & 127;
                const bf16x8 v = *(const bf16x8*)&Es[elem];
                const int t = tb + mm;
                const int hh = hh0 + (cc >> 6);
                bf16* const dst = (n0 < 1024) ? qw : kw;
                *(bf16x8*)(dst + ((size_t)((bq << 4) + hh) << 16) + ((size_t)t << 6)
                           + (cc & 63)) = v;
            }
        }
    } else {
        #pragma unroll
        for (int mf = 0; mf < WMF; ++mf)
            #pragma unroll
            for (int nf = 0; nf < NF; ++nf) {
                const int ng = n0 + wcb + (nf << 4) + l16;
                const float bs = bias[ng];
                #pragma unroll
                for (int j = 0; j < 4; ++j) {
                    const int mg = m0 + wrb + (mf << 4) + (g << 2) + j;
                    outf[(size_t)mg * N + ng] = acc[mf][nf][j] + bs;
                }
            }
    }
}

// ---------------- flash attention: swapped-QK^T, fused dual-q-block kv sweep ----------------
// Q,K [bh][1024][64]; Vt [bh][64][1024 t-permuted]; out att [4096][1024] bf16.
// grid (64, 8): blockIdx.x = bh (same-head blocks land on one XCD).
// Block bx owns q-blocks q1=bx and q2=15-bx over ONE kv sweep kt=0..15-bx:
// each tile staged once (12.5 avg vs 17), both q-blocks consume it.
__global__ __launch_bounds__(256)
void attn_k(const bf16* __restrict__ Qp, const bf16* __restrict__ Kp,
            const bf16* __restrict__ Vt, bf16* __restrict__ att)
{
    __shared__ __align__(16) bf16 Kl0[64 * 64], Kl1[64 * 64];
    __shared__ __align__(16) bf16 Vl0[64 * 64], Vl1[64 * 64];

    const int bh = blockIdx.x;          // 0..63
    const int bx = blockIdx.y;          // 0..7
    const int b  = bh >> 4, h = bh & 15;

    const int tid  = threadIdx.x;
    const int lane = tid & 63;
    const int wid  = tid >> 6;
    const int g    = lane >> 4;
    const int l16  = lane & 15;
    const int g8   = g << 3;

    const size_t hb = (size_t)bh << 16;
    const bf16* Qh = Qp + hb;
    const bf16* Kh = Kp + hb;
    const bf16* Vh = Vt + hb;

    // staging: 8 rows x 128B per instr; source chunk XOR-preswizzled by row&7
    const int srow = lane >> 3;
    const int sswz = ((lane & 7) ^ srow) << 3;
    const int kr0  = (wid << 4) + srow;
    const int kr1  = kr0 + 8;
    const int dst0 = (wid << 4) << 6;
    const int dst1 = ((wid << 4) + 8) << 6;

    // fragment read offsets (elems), swizzle-matched; rows = kv (K) or d (V^T)
    int offKV[2][4];
    #pragma unroll
    for (int ks = 0; ks < 2; ++ks)
        #pragma unroll
        for (int cb = 0; cb < 4; ++cb) {
            const int r = (cb << 4) + l16;
            offKV[ks][cb] = (r << 6) + (((((ks << 2) + g)) ^ (r & 7)) << 3);
        }

    const float QSCALE = 0.125f * 1.44269504f;

    const int q1b = bx;
    const int q2b = 15 - bx;
    const int nkt = q2b;
    const int qloc = (wid << 4) + l16;

    // hoist both Q fragment sets, pre-scaled
    const bf16* qp1 = Qh + ((size_t)((q1b << 6) + qloc) << 6) + g8;
    const bf16* qp2 = Qh + ((size_t)((q2b << 6) + qloc) << 6) + g8;
    bf16x8 q1f0 = *(const bf16x8*)qp1, q1f1 = *(const bf16x8*)(qp1 + 32);
    bf16x8 q2f0 = *(const bf16x8*)qp2, q2f1 = *(const bf16x8*)(qp2 + 32);
    #pragma unroll
    for (int e = 0; e < 8; ++e) {
        q1f0[e] = (bf16)(QSCALE * (float)q1f0[e]);
        q1f1[e] = (bf16)(QSCALE * (float)q1f1[e]);
        q2f0[e] = (bf16)(QSCALE * (float)q2f0[e]);
        q2f1[e] = (bf16)(QSCALE * (float)q2f1[e]);
    }

    f32x4 acc1[4], acc2[4];
    float m1 = -1e30f, l1 = 0.f, m2 = -1e30f, l2 = 0.f;
    #pragma unroll
    for (int i = 0; i < 4; ++i) { acc1[i] = zero4(); acc2[i] = zero4(); }

    // prologue: stage kv tile 0
    gl_lds16(Kh + ((size_t)kr0 << 6) + sswz, Kl0 + dst0);
    gl_lds16(Kh + ((size_t)kr1 << 6) + sswz, Kl0 + dst1);
    gl_lds16(Vh + ((size_t)kr0 << 10) + sswz, Vl0 + dst0);
    gl_lds16(Vh + ((size_t)kr1 << 10) + sswz, Vl0 + dst1);
    __syncthreads();

    for (int kt = 0; kt <= nkt; ++kt) {
        const bool odd = kt & 1;
        if (kt < nkt) {
            const int kv1 = (kt + 1) << 6;
            bf16* Kn = odd ? Kl0 : Kl1;
            bf16* Vn = odd ? Vl0 : Vl1;
            gl_lds16(Kh + ((size_t)(kv1 + kr0) << 6) + sswz, Kn + dst0);
            gl_lds16(Kh + ((size_t)(kv1 + kr1) << 6) + sswz, Kn + dst1);
            gl_lds16(Vh + ((size_t)kr0 << 10) + kv1 + sswz, Vn + dst0);
            gl_lds16(Vh + ((size_t)kr1 << 10) + kv1 + sswz, Vn + dst1);
        }
        const bf16* Kc = odd ? Kl1 : Kl0;
        const bf16* Vc = odd ? Vl1 : Vl0;

        // preload K fragments (shared by both q-blocks)
        bf16x8 kf[2][4];
        #pragma unroll
        for (int ks = 0; ks < 2; ++ks)
            #pragma unroll
            for (int cb = 0; cb < 4; ++cb)
                kf[ks][cb] = *(const bf16x8*)&Kc[offKV[ks][cb]];

        // ---- q2 (always active): S^T, softmax, P, PV ----
        {
            f32x4 sacc[4];
            #pragma unroll
            for (int cb = 0; cb < 4; ++cb) sacc[cb] = zero4();
            #pragma unroll
            for (int cb = 0; cb < 4; ++cb) sacc[cb] = MFMA16(kf[0][cb], q2f0, sacc[cb]);
            #pragma unroll
            for (int cb = 0; cb < 4; ++cb) sacc[cb] = MFMA16(kf[1][cb], q2f1, sacc[cb]);
            if (kt == q2b) {
                #pragma unroll
                for (int cb = 0; cb < 4; ++cb)
                    #pragma unroll
                    for (int j = 0; j < 4; ++j)
                        if (((cb << 4) + (g << 2) + j) > qloc) sacc[cb][j] = -1e30f;
            }
            float pm = sacc[0][0];
            #pragma unroll
            for (int cb = 0; cb < 4; ++cb)
                #pragma unroll
                for (int j = 0; j < 4; ++j) pm = fmaxf(pm, sacc[cb][j]);
            pm = fmaxf(pm, __shfl_xor(pm, 16));
            pm = fmaxf(pm, __shfl_xor(pm, 32));
            if (__any(pm > m2 + 8.f)) {
                const float mn = fmaxf(m2, pm);
                const float sc = __builtin_amdgcn_exp2f(m2 - mn);
                m2 = mn; l2 *= sc;
                #pragma unroll
                for (int db = 0; db < 4; ++db)
                    #pragma unroll
                    for (int j = 0; j < 4; ++j) acc2[db][j] *= sc;
            }
            float rsum = 0.f;
            #pragma unroll
            for (int cb = 0; cb < 4; ++cb)
                #pragma unroll
                for (int j = 0; j < 4; ++j) {
                    const float p = __builtin_amdgcn_exp2f(sacc[cb][j] - m2);
                    sacc[cb][j] = p;
                    rsum += p;
                }
            rsum += __shfl_xor(rsum, 16);
            rsum += __shfl_xor(rsum, 32);
            l2 += rsum;
            bf16x8 pf0, pf1;
            #pragma unroll
            for (int i = 0; i < 8; ++i) {
                pf0[i] = (bf16)sacc[i >> 2][i & 3];
                pf1[i] = (bf16)sacc[2 + (i >> 2)][i & 3];
            }
            #pragma unroll
            for (int db = 0; db < 4; ++db) {
                const bf16x8 vf = *(const bf16x8*)&Vc[offKV[0][db]];
                acc2[db] = MFMA16(vf, pf0, acc2[db]);
            }
            #pragma unroll
            for (int db = 0; db < 4; ++db) {
                const bf16x8 vf = *(const bf16x8*)&Vc[offKV[1][db]];
                acc2[db] = MFMA16(vf, pf1, acc2[db]);
            }
        }

        // ---- q1 (active while kt <= q1b) ----
        if (kt <= q1b) {
            f32x4 sacc[4];
            #pragma unroll
            for (int cb = 0; cb < 4; ++cb) sacc[cb] = zero4();
            #pragma unroll
            for (int cb = 0; cb < 4; ++cb) sacc[cb] = MFMA16(kf[0][cb], q1f0, sacc[cb]);
            #pragma unroll
            for (int cb = 0; cb < 4; ++cb) sacc[cb] = MFMA16(kf[1][cb], q1f1, sacc[cb]);
            if (kt == q1b) {
                #pragma unroll
                for (int cb = 0; cb < 4; ++cb)
                    #pragma unroll
                    for (int j = 0; j < 4; ++j)
                        if (((cb << 4) + (g << 2) + j) > qloc) sacc[cb][j] = -1e30f;
            }
            float pm = sacc[0][0];
            #pragma unroll
            for (int cb = 0; cb < 4; ++cb)
                #pragma unroll
                for (int j = 0; j < 4; ++j) pm = fmaxf(pm, sacc[cb][j]);
            pm = fmaxf(pm, __shfl_xor(pm, 16));
            pm = fmaxf(pm, __shfl_xor(pm, 32));
            if (__any(pm > m1 + 8.f)) {
                const float mn = fmaxf(m1, pm);
                const float sc = __builtin_amdgcn_exp2f(m1 - mn);
                m1 = mn; l1 *= sc;
                #pragma unroll
                for (int db = 0; db < 4; ++db)
                    #pragma unroll
                    for (int j = 0; j < 4; ++j) acc1[db][j] *= sc;
            }
            float rsum = 0.f;
            #pragma unroll
            for (int cb = 0; cb < 4; ++cb)
                #pragma unroll
                for (int j = 0; j < 4; ++j) {
                    const float p = __builtin_amdgcn_exp2f(sacc[cb][j] - m1);
                    sacc[cb][j] = p;
                    rsum += p;
                }
            rsum += __shfl_xor(rsum, 16);
            rsum += __shfl_xor(rsum, 32);
            l1 += rsum;
            bf16x8 pf0, pf1;
            #pragma unroll
            for (int i = 0; i < 8; ++i) {
                pf0[i] = (bf16)sacc[i >> 2][i & 3];
                pf1[i] = (bf16)sacc[2 + (i >> 2)][i & 3];
            }
            #pragma unroll
            for (int db = 0; db < 4; ++db) {
                const bf16x8 vf = *(const bf16x8*)&Vc[offKV[0][db]];
                acc1[db] = MFMA16(vf, pf0, acc1[db]);
            }
            #pragma unroll
            for (int db = 0; db < 4; ++db) {
                const bf16x8 vf = *(const bf16x8*)&Vc[offKV[1][db]];
                acc1[db] = MFMA16(vf, pf1, acc1[db]);
            }
        }
        __syncthreads();
    }

    // ---- epilogue: lane owns q-col l16; d = 16db+4g+j ----
    {
        const float inv = 1.f / l2;
        const int t = (q2b << 6) + qloc;
        #pragma unroll
        for (int db = 0; db < 4; ++db) {
            bf16x4 o;
            #pragma unroll
            for (int j = 0; j < 4; ++j) o[j] = (bf16)(acc2[db][j] * inv);
            *(bf16x4*)(att + (((size_t)b << 10) + t) * 1024 + (h << 6) + (db << 4) + (g << 2)) = o;
        }
    }
    {
        const float inv = 1.f / l1;
        const int t = (q1b << 6) + qloc;
        #pragma unroll
        for (int db = 0; db < 4; ++db) {
            bf16x4 o;
            #pragma unroll
            for (int j = 0; j < 4; ++j) o[j] = (bf16)(acc1[db][j] * inv);
            *(bf16x4*)(att + (((size_t)b << 10) + t) * 1024 + (h << 6) + (db << 4) + (g << 2)) = o;
        }
    }
}

extern "C" void kernel_launch(void* const* d_in, const int* in_sizes, int n_in,
                              void* d_out, int out_size, void* d_ws, size_t ws_size,
                              hipStream_t stream)
{
    const float* x      = (const float*)d_in[0];
    const float* w_attn = (const float*)d_in[1];
    const float* b_attn = (const float*)d_in[2];
    const float* w_proj = (const float*)d_in[3];
    const float* b_proj = (const float*)d_in[4];
    float* out = (float*)d_out;

    // workspace layout (bf16 elems)
    bf16* xb  = (bf16*)d_ws;                        // [4096][1024]
    bf16* wT  = xb  + (size_t)4096 * 1024;          // [3072][1024]
    bf16* wpT = wT  + (size_t)3072 * 1024;          // [1024][1024]
    bf16* qw  = wpT + (size_t)1024 * 1024;          // [64 bh][1024 t][64 d]
    bf16* kw  = qw  + (size_t)64 * 1024 * 64;       // [64 bh][1024 t][64 d]
    bf16* vw  = kw  + (size_t)64 * 1024 * 64;       // [64 bh][64 d][1024 t']
    bf16* aw  = vw  + (size_t)64 * 1024 * 64;       // [4096][1024]

    conv_k<<<2048, 256, 0, stream>>>(x, xb, 4096 * 1024);
    transp_k<<<dim3(48, 16), 256, 0, stream>>>(w_attn, wT, 1024, 3072);
    transp_k<<<dim3(16, 16), 256, 0, stream>>>(w_proj, wpT, 1024, 1024);

    gemm_bt<0><<<dim3(24, 16), 256, 0, stream>>>(xb, wT, b_attn, qw, kw, vw,
                                                 nullptr, 4096, 3072, 1024);
    attn_k<<<dim3(64, 8), 256, 0, stream>>>(qw, kw, vw, aw);
    gemm_bt<1><<<dim3(16, 32), 256, 0, stream>>>(aw, wpT, b_proj, nullptr, nullptr, nullptr,
                                                 out, 4096, 1024, 1024);
}

// Round 10
// 91.672 us; speedup vs baseline: 1.1329x; 1.1329x over previous
//
#include <hip/hip_runtime.h>

typedef __bf16 bf16;
typedef float f32x4 __attribute__((ext_vector_type(4)));
typedef bf16 bf16x4 __attribute__((ext_vector_type(4)));
typedef bf16 bf16x8 __attribute__((ext_vector_type(8)));

#define MFMA16(a, b, c) __builtin_amdgcn_mfma_f32_16x16x32_bf16((a), (b), (c), 0, 0, 0)

__device__ __forceinline__ f32x4 zero4() {
    f32x4 z; z[0] = 0.f; z[1] = 0.f; z[2] = 0.f; z[3] = 0.f; return z;
}
// async global -> LDS, 16B/lane. LDS dest = wave-uniform base + lane*16.
__device__ __forceinline__ void gl_lds16(const bf16* g, bf16* l) {
    __builtin_amdgcn_global_load_lds(
        (const __attribute__((address_space(1))) void*)g,
        (__attribute__((address_space(3))) void*)l, 16, 0, 0);
}

// ---------------- prep: f32 -> bf16 elementwise ----------------
__global__ __launch_bounds__(256) void conv_k(const float* __restrict__ src,
                                              bf16* __restrict__ dst, int n)
{
    const int i = (blockIdx.x * 256 + threadIdx.x) * 8;
    if (i >= n) return;
    const float4 a = *(const float4*)(src + i);
    const float4 b = *(const float4*)(src + i + 4);
    bf16x8 o;
    o[0] = (bf16)a.x; o[1] = (bf16)a.y; o[2] = (bf16)a.z; o[3] = (bf16)a.w;
    o[4] = (bf16)b.x; o[5] = (bf16)b.y; o[6] = (bf16)b.z; o[7] = (bf16)b.w;
    *(bf16x8*)(dst + i) = o;
}

// ---------------- prep: transpose+convert w [K][N] f32 -> wT [N][K] bf16 ----------------
__global__ __launch_bounds__(256) void transp_k(const float* __restrict__ src,
                                                bf16* __restrict__ dst, int K, int N)
{
    __shared__ bf16 Ls[64][72];
    const int tid = threadIdx.x;
    const int k0 = blockIdx.y << 6;
    const int n0 = blockIdx.x << 6;
    #pragma unroll
    for (int it = 0; it < 4; ++it) {
        const int lin = (it << 10) + (tid << 2);
        const int r = lin >> 6, c = lin & 63;
        const float4 v = *(const float4*)(src + (size_t)(k0 + r) * N + n0 + c);
        bf16x4 o; o[0] = (bf16)v.x; o[1] = (bf16)v.y; o[2] = (bf16)v.z; o[3] = (bf16)v.w;
        *(bf16x4*)&Ls[r][c] = o;
    }
    __syncthreads();
    #pragma unroll
    for (int it = 0; it < 2; ++it) {
        const int lin = (it << 11) + (tid << 3);
        const int nn = lin >> 6, kk = lin & 63;
        bf16x8 o;
        #pragma unroll
        for (int j = 0; j < 8; ++j) o[j] = Ls[kk + j][nn];
        *(bf16x8*)(dst + (size_t)(n0 + nn) * K + k0 + kk) = o;
    }
}

// ---------------- bf16 GEMM, B^T input, depth-2 counted-vmcnt pipeline, BK=32 ----------------
// BM=128. Launched with a 1-D grid; XCD-aware 2-D chunked swizzle decodes (by,bx) so each
// XCD's resident blocks form an 8(by) x NBX/2(bx) super-tile: A+B panels ~5MB -> L2-resident.
// MODE 0 (BN=128): scatter q/k packed [bh][t][d] + v transposed+t-permuted [bh][d][t'] via LDS-pack
// MODE 1 (BN=64):  f32 out[M][N] + bias, direct stores
template <int MODE, int BN>
__global__ __launch_bounds__(256)
void gemm_bt(const bf16* __restrict__ A, const bf16* __restrict__ Bt,
             const float* __restrict__ bias,
             bf16* __restrict__ qw, bf16* __restrict__ kw, bf16* __restrict__ vw,
             float* __restrict__ outf, int M, int N, int K)
{
    constexpr int BK = 32;
    constexpr int MF = (BN == 128) ? 4 : 2;
    constexpr int NF = 4;
    constexpr int AE = 128 * BK;
    constexpr int BE = BN * BK;
    constexpr int LPI = (BN == 128) ? 4 : 3;     // gl_lds issues per wave per K-step

    __shared__ __align__(16) bf16 smem[3 * (AE + BE)];
    bf16* const Asb = smem;
    bf16* const Bsb = smem + 3 * AE;

    const int tid  = threadIdx.x;
    const int lane = tid & 63;
    const int wid  = tid >> 6;
    const int l16  = lane & 15;
    const int g    = lane >> 4;
    const int wrb  = (BN == 128) ? ((wid >> 1) << 6) : (wid << 5);
    const int wcb  = (BN == 128) ? ((wid & 1) << 6) : 0;

    // ---- XCD-aware bijective 2-D swizzle (grid is 1-D) ----
    // MODE0: 768 blocks -> xcd gets 8(by) x 12(bx); MODE1: 512 -> 8 x 8.
    const int p   = blockIdx.x;
    const int xcd = p & 7;
    const int r   = p >> 3;
    int by, bx;
    if (MODE == 0) { by = ((xcd >> 1) << 3) + r / 12; bx = (xcd & 1) * 12 + r % 12; }
    else           { by = ((xcd >> 1) << 3) + (r >> 3); bx = ((xcd & 1) << 3) + (r & 7); }
    const int m0 = by << 7;
    const int n0 = bx * BN;

    // staging: 16 rows x 64B per instr; source chunk XOR-preswizzled by (row>>1)&3
    const int srow = lane >> 2;
    const int schk = lane & 3;
    const int rA0 = (wid << 5) + srow;
    const int rA1 = rA0 + 16;
    const int rB0 = wid * (BN / 4) + srow;
    const int rB1 = rB0 + 16;
    const bf16* pa0 = A  + (size_t)(m0 + rA0) * K + ((schk ^ ((rA0 >> 1) & 3)) << 3);
    const bf16* pa1 = A  + (size_t)(m0 + rA1) * K + ((schk ^ ((rA1 >> 1) & 3)) << 3);
    const bf16* pb0 = Bt + (size_t)(n0 + rB0) * K + ((schk ^ ((rB0 >> 1) & 3)) << 3);
    const bf16* pb1 = Bt + (size_t)(n0 + rB1) * K + ((schk ^ ((rB1 >> 1) & 3)) << 3);
    const int dA0 = (wid << 5) * BK, dA1 = dA0 + 16 * BK;
    const int dB0 = (wid * (BN / 4)) * BK, dB1 = dB0 + 16 * BK;

    auto issue = [&](bf16* ab, bf16* bb) {
        gl_lds16(pa0, ab + dA0); gl_lds16(pa1, ab + dA1);
        gl_lds16(pb0, bb + dB0);
        if constexpr (BN == 128) gl_lds16(pb1, bb + dB1);
        pa0 += BK; pa1 += BK; pb0 += BK; pb1 += BK;
    };

    // fragment read offsets (elems), swizzle-matched
    int offA[MF], offB[NF];
    #pragma unroll
    for (int mf = 0; mf < MF; ++mf) {
        const int rr = wrb + (mf << 4) + l16;
        offA[mf] = rr * BK + ((g ^ ((rr >> 1) & 3)) << 3);
    }
    #pragma unroll
    for (int nf = 0; nf < NF; ++nf) {
        const int rr = wcb + (nf << 4) + l16;
        offB[nf] = rr * BK + ((g ^ ((rr >> 1) & 3)) << 3);
    }

    f32x4 acc[MF][NF];
    #pragma unroll
    for (int i = 0; i < MF; ++i)
        #pragma unroll
        for (int j = 0; j < NF; ++j) acc[i][j] = zero4();

    const int nk = K >> 5;
    issue(Asb, Bsb);
    issue(Asb + AE, Bsb + BE);

    for (int kt = 0; kt < nk; ++kt) {
        if (kt == nk - 1) {
            asm volatile("s_waitcnt vmcnt(0)" ::: "memory");
        } else {
            if constexpr (LPI == 4) asm volatile("s_waitcnt vmcnt(4)" ::: "memory");
            else                    asm volatile("s_waitcnt vmcnt(3)" ::: "memory");
        }
        __builtin_amdgcn_s_barrier();            // tile kt staged for all waves
        const int nxt = kt + 2;
        if (nxt < nk) {
            const int s = nxt - (nxt / 3) * 3;
            issue(Asb + s * AE, Bsb + s * BE);
        }
        const int c = kt - (kt / 3) * 3;
        const bf16* ac = Asb + c * AE;
        const bf16* bc = Bsb + c * BE;
        bf16x8 af[MF], bfr[NF];
        #pragma unroll
        for (int mf = 0; mf < MF; ++mf) af[mf] = *(const bf16x8*)&ac[offA[mf]];
        #pragma unroll
        for (int nf = 0; nf < NF; ++nf) bfr[nf] = *(const bf16x8*)&bc[offB[nf]];
        __builtin_amdgcn_s_setprio(1);
        #pragma unroll
        for (int mf = 0; mf < MF; ++mf)
            #pragma unroll
            for (int nf = 0; nf < NF; ++nf)
                acc[mf][nf] = MFMA16(af[mf], bfr[nf], acc[mf][nf]);
        __builtin_amdgcn_s_setprio(0);
    }
    __syncthreads();                             // reads done before smem reuse

    if (MODE == 0) {
        // ---- LDS-pack epilogue: 128x128 bf16 tile reusing smem ----
        bf16* const Es = smem;
        const int bq  = m0 >> 10;
        const int tb  = m0 & 1023;
        const int hh0 = (n0 & 1023) >> 6;
        const bool isV = (n0 >= 2048);
        if (isV) {
            #pragma unroll
            for (int mf = 0; mf < MF; ++mf)
                #pragma unroll
                for (int nf = 0; nf < NF; ++nf) {
                    const int nn = wcb + (nf << 4) + l16;
                    const float bs = bias[n0 + nn];
                    bf16x4 pq;
                    #pragma unroll
                    for (int j = 0; j < 4; ++j) pq[j] = (bf16)(acc[mf][nf][j] + bs);
                    // transposed + PV-kmap permuted: t = 32s+16h+4g'+j -> pos 32s+8g'+4h+j
                    const int m = wrb + (mf << 4) + (g << 2);
                    const int pp = ((m >> 5) << 5) + (((m >> 2) & 3) << 3) + (((m >> 4) & 1) << 2);
                    *(bf16x4*)&Es[nn * 128 + pp] = pq;
                }
        } else {
            #pragma unroll
            for (int mf = 0; mf < MF; ++mf)
                #pragma unroll
                for (int nf = 0; nf < NF; ++nf) {
                    const int nn = wcb + (nf << 4) + l16;
                    const float bs = bias[n0 + nn];
                    #pragma unroll
                    for (int j = 0; j < 4; ++j) {
                        const int mm = wrb + (mf << 4) + (g << 2) + j;
                        Es[mm * 128 + nn] = (bf16)(acc[mf][nf][j] + bs);
                    }
                }
        }
        __syncthreads();
        #pragma unroll
        for (int it = 0; it < 8; ++it) {
            const int idx = (it << 8) + tid;
            const int row = idx >> 4, ch = idx & 15;
            const bf16x8 v = *(const bf16x8*)&Es[row * 128 + (ch << 3)];
            if (isV) {
                const int dd = row & 63, hh = hh0 + (row >> 6);
                *(bf16x8*)(vw + ((size_t)((bq << 4) + hh) << 16) + ((size_t)dd << 10)
                           + tb + (ch << 3)) = v;
            } else {
                const int t = tb + row;
                const int cc = ch << 3;
                const int hh = hh0 + (cc >> 6);
                bf16* const dst = (n0 < 1024) ? qw : kw;
                *(bf16x8*)(dst + ((size_t)((bq << 4) + hh) << 16) + ((size_t)t << 6)
                           + (cc & 63)) = v;
            }
        }
    } else {
        #pragma unroll
        for (int mf = 0; mf < MF; ++mf)
            #pragma unroll
            for (int nf = 0; nf < NF; ++nf) {
                const int ng = n0 + wcb + (nf << 4) + l16;
                const float bs = bias[ng];
                #pragma unroll
                for (int j = 0; j < 4; ++j) {
                    const int mg = m0 + wrb + (mf << 4) + (g << 2) + j;
                    outf[(size_t)mg * N + ng] = acc[mf][nf][j] + bs;
                }
            }
    }
}

// ---------------- flash attention: swapped-QK^T, fused dual-q-block kv sweep ----------------
// Q,K [bh][1024][64]; Vt [bh][64][1024 t-permuted]; out att [4096][1024] bf16.
// grid (64, 8): blockIdx.x = bh (same-head blocks land on one XCD).
// Block bx owns q-blocks q1=bx and q2=15-bx over ONE kv sweep kt=0..15-bx.
__global__ __launch_bounds__(256)
void attn_k(const bf16* __restrict__ Qp, const bf16* __restrict__ Kp,
            const bf16* __restrict__ Vt, bf16* __restrict__ att)
{
    __shared__ __align__(16) bf16 Kl0[64 * 64], Kl1[64 * 64];
    __shared__ __align__(16) bf16 Vl0[64 * 64], Vl1[64 * 64];

    const int bh = blockIdx.x;          // 0..63
    const int bx = blockIdx.y;          // 0..7
    const int b  = bh >> 4, h = bh & 15;

    const int tid  = threadIdx.x;
    const int lane = tid & 63;
    const int wid  = tid >> 6;
    const int g    = lane >> 4;
    const int l16  = lane & 15;
    const int g8   = g << 3;

    const size_t hb = (size_t)bh << 16;
    const bf16* Qh = Qp + hb;
    const bf16* Kh = Kp + hb;
    const bf16* Vh = Vt + hb;

    // staging: 8 rows x 128B per instr; source chunk XOR-preswizzled by row&7
    const int srow = lane >> 3;
    const int sswz = ((lane & 7) ^ srow) << 3;
    const int kr0  = (wid << 4) + srow;
    const int kr1  = kr0 + 8;
    const int dst0 = (wid << 4) << 6;
    const int dst1 = ((wid << 4) + 8) << 6;

    // fragment read offsets (elems), swizzle-matched; rows = kv (K) or d (V^T)
    int offKV[2][4];
    #pragma unroll
    for (int ks = 0; ks < 2; ++ks)
        #pragma unroll
        for (int cb = 0; cb < 4; ++cb) {
            const int r = (cb << 4) + l16;
            offKV[ks][cb] = (r << 6) + (((((ks << 2) + g)) ^ (r & 7)) << 3);
        }

    const float QSCALE = 0.125f * 1.44269504f;

    const int q1b = bx;
    const int q2b = 15 - bx;
    const int nkt = q2b;
    const int qloc = (wid << 4) + l16;

    // hoist both Q fragment sets, pre-scaled
    const bf16* qp1 = Qh + ((size_t)((q1b << 6) + qloc) << 6) + g8;
    const bf16* qp2 = Qh + ((size_t)((q2b << 6) + qloc) << 6) + g8;
    bf16x8 q1f0 = *(const bf16x8*)qp1, q1f1 = *(const bf16x8*)(qp1 + 32);
    bf16x8 q2f0 = *(const bf16x8*)qp2, q2f1 = *(const bf16x8*)(qp2 + 32);
    #pragma unroll
    for (int e = 0; e < 8; ++e) {
        q1f0[e] = (bf16)(QSCALE * (float)q1f0[e]);
        q1f1[e] = (bf16)(QSCALE * (float)q1f1[e]);
        q2f0[e] = (bf16)(QSCALE * (float)q2f0[e]);
        q2f1[e] = (bf16)(QSCALE * (float)q2f1[e]);
    }

    f32x4 acc1[4], acc2[4];
    float m1 = -1e30f, l1 = 0.f, m2 = -1e30f, l2 = 0.f;
    #pragma unroll
    for (int i = 0; i < 4; ++i) { acc1[i] = zero4(); acc2[i] = zero4(); }

    // prologue: stage kv tile 0
    gl_lds16(Kh + ((size_t)kr0 << 6) + sswz, Kl0 + dst0);
    gl_lds16(Kh + ((size_t)kr1 << 6) + sswz, Kl0 + dst1);
    gl_lds16(Vh + ((size_t)kr0 << 10) + sswz, Vl0 + dst0);
    gl_lds16(Vh + ((size_t)kr1 << 10) + sswz, Vl0 + dst1);
    __syncthreads();

    for (int kt = 0; kt <= nkt; ++kt) {
        const bool odd = kt & 1;
        if (kt < nkt) {
            const int kv1 = (kt + 1) << 6;
            bf16* Kn = odd ? Kl0 : Kl1;
            bf16* Vn = odd ? Vl0 : Vl1;
            gl_lds16(Kh + ((size_t)(kv1 + kr0) << 6) + sswz, Kn + dst0);
            gl_lds16(Kh + ((size_t)(kv1 + kr1) << 6) + sswz, Kn + dst1);
            gl_lds16(Vh + ((size_t)kr0 << 10) + kv1 + sswz, Vn + dst0);
            gl_lds16(Vh + ((size_t)kr1 << 10) + kv1 + sswz, Vn + dst1);
        }
        const bf16* Kc = odd ? Kl1 : Kl0;
        const bf16* Vc = odd ? Vl1 : Vl0;

        // preload K fragments (shared by both q-blocks)
        bf16x8 kf[2][4];
        #pragma unroll
        for (int ks = 0; ks < 2; ++ks)
            #pragma unroll
            for (int cb = 0; cb < 4; ++cb)
                kf[ks][cb] = *(const bf16x8*)&Kc[offKV[ks][cb]];

        // ---- q2 (always active) ----
        {
            f32x4 sacc[4];
            #pragma unroll
            for (int cb = 0; cb < 4; ++cb) sacc[cb] = zero4();
            #pragma unroll
            for (int cb = 0; cb < 4; ++cb) sacc[cb] = MFMA16(kf[0][cb], q2f0, sacc[cb]);
            #pragma unroll
            for (int cb = 0; cb < 4; ++cb) sacc[cb] = MFMA16(kf[1][cb], q2f1, sacc[cb]);
            if (kt == q2b) {
                #pragma unroll
                for (int cb = 0; cb < 4; ++cb)
                    #pragma unroll
                    for (int j = 0; j < 4; ++j)
                        if (((cb << 4) + (g << 2) + j) > qloc) sacc[cb][j] = -1e30f;
            }
            float pm = sacc[0][0];
            #pragma unroll
            for (int cb = 0; cb < 4; ++cb)
                #pragma unroll
                for (int j = 0; j < 4; ++j) pm = fmaxf(pm, sacc[cb][j]);
            pm = fmaxf(pm, __shfl_xor(pm, 16));
            pm = fmaxf(pm, __shfl_xor(pm, 32));
            if (__any(pm > m2 + 8.f)) {
                const float mn = fmaxf(m2, pm);
                const float sc = __builtin_amdgcn_exp2f(m2 - mn);
                m2 = mn; l2 *= sc;
                #pragma unroll
                for (int db = 0; db < 4; ++db)
                    #pragma unroll
                    for (int j = 0; j < 4; ++j) acc2[db][j] *= sc;
            }
            float rsum = 0.f;
            #pragma unroll
            for (int cb = 0; cb < 4; ++cb)
                #pragma unroll
                for (int j = 0; j < 4; ++j) {
                    const float pv = __builtin_amdgcn_exp2f(sacc[cb][j] - m2);
                    sacc[cb][j] = pv;
                    rsum += pv;
                }
            rsum += __shfl_xor(rsum, 16);
            rsum += __shfl_xor(rsum, 32);
            l2 += rsum;
            bf16x8 pf0, pf1;
            #pragma unroll
            for (int i = 0; i < 8; ++i) {
                pf0[i] = (bf16)sacc[i >> 2][i & 3];
                pf1[i] = (bf16)sacc[2 + (i >> 2)][i & 3];
            }
            #pragma unroll
            for (int db = 0; db < 4; ++db) {
                const bf16x8 vf = *(const bf16x8*)&Vc[offKV[0][db]];
                acc2[db] = MFMA16(vf, pf0, acc2[db]);
            }
            #pragma unroll
            for (int db = 0; db < 4; ++db) {
                const bf16x8 vf = *(const bf16x8*)&Vc[offKV[1][db]];
                acc2[db] = MFMA16(vf, pf1, acc2[db]);
            }
        }

        // ---- q1 (active while kt <= q1b) ----
        if (kt <= q1b) {
            f32x4 sacc[4];
            #pragma unroll
            for (int cb = 0; cb < 4; ++cb) sacc[cb] = zero4();
            #pragma unroll
            for (int cb = 0; cb < 4; ++cb) sacc[cb] = MFMA16(kf[0][cb], q1f0, sacc[cb]);
            #pragma unroll
            for (int cb = 0; cb < 4; ++cb) sacc[cb] = MFMA16(kf[1][cb], q1f1, sacc[cb]);
            if (kt == q1b) {
                #pragma unroll
                for (int cb = 0; cb < 4; ++cb)
                    #pragma unroll
                    for (int j = 0; j < 4; ++j)
                        if (((cb << 4) + (g << 2) + j) > qloc) sacc[cb][j] = -1e30f;
            }
            float pm = sacc[0][0];
            #pragma unroll
            for (int cb = 0; cb < 4; ++cb)
                #pragma unroll
                for (int j = 0; j < 4; ++j) pm = fmaxf(pm, sacc[cb][j]);
            pm = fmaxf(pm, __shfl_xor(pm, 16));
            pm = fmaxf(pm, __shfl_xor(pm, 32));
            if (__any(pm > m1 + 8.f)) {
                const float mn = fmaxf(m1, pm);
                const float sc = __builtin_amdgcn_exp2f(m1 - mn);
                m1 = mn; l1 *= sc;
                #pragma unroll
                for (int db = 0; db < 4; ++db)
                    #pragma unroll
                    for (int j = 0; j < 4; ++j) acc1[db][j] *= sc;
            }
            float rsum = 0.f;
            #pragma unroll
            for (int cb = 0; cb < 4; ++cb)
                #pragma unroll
                for (int j = 0; j < 4; ++j) {
                    const float pv = __builtin_amdgcn_exp2f(sacc[cb][j] - m1);
                    sacc[cb][j] = pv;
                    rsum += pv;
                }
            rsum += __shfl_xor(rsum, 16);
            rsum += __shfl_xor(rsum, 32);
            l1 += rsum;
            bf16x8 pf0, pf1;
            #pragma unroll
            for (int i = 0; i < 8; ++i) {
                pf0[i] = (bf16)sacc[i >> 2][i & 3];
                pf1[i] = (bf16)sacc[2 + (i >> 2)][i & 3];
            }
            #pragma unroll
            for (int db = 0; db < 4; ++db) {
                const bf16x8 vf = *(const bf16x8*)&Vc[offKV[0][db]];
                acc1[db] = MFMA16(vf, pf0, acc1[db]);
            }
            #pragma unroll
            for (int db = 0; db < 4; ++db) {
                const bf16x8 vf = *(const bf16x8*)&Vc[offKV[1][db]];
                acc1[db] = MFMA16(vf, pf1, acc1[db]);
            }
        }
        __syncthreads();
    }

    // ---- epilogue: lane owns q-col l16; d = 16db+4g+j ----
    {
        const float inv = 1.f / l2;
        const int t = (q2b << 6) + qloc;
        #pragma unroll
        for (int db = 0; db < 4; ++db) {
            bf16x4 o;
            #pragma unroll
            for (int j = 0; j < 4; ++j) o[j] = (bf16)(acc2[db][j] * inv);
            *(bf16x4*)(att + (((size_t)b << 10) + t) * 1024 + (h << 6) + (db << 4) + (g << 2)) = o;
        }
    }
    {
        const float inv = 1.f / l1;
        const int t = (q1b << 6) + qloc;
        #pragma unroll
        for (int db = 0; db < 4; ++db) {
            bf16x4 o;
            #pragma unroll
            for (int j = 0; j < 4; ++j) o[j] = (bf16)(acc1[db][j] * inv);
            *(bf16x4*)(att + (((size_t)b << 10) + t) * 1024 + (h << 6) + (db << 4) + (g << 2)) = o;
        }
    }
}

extern "C" void kernel_launch(void* const* d_in, const int* in_sizes, int n_in,
                              void* d_out, int out_size, void* d_ws, size_t ws_size,
                              hipStream_t stream)
{
    const float* x      = (const float*)d_in[0];
    const float* w_attn = (const float*)d_in[1];
    const float* b_attn = (const float*)d_in[2];
    const float* w_proj = (const float*)d_in[3];
    const float* b_proj = (const float*)d_in[4];
    float* out = (float*)d_out;

    // workspace layout (bf16 elems)
    bf16* xb  = (bf16*)d_ws;                        // [4096][1024]
    bf16* wT  = xb  + (size_t)4096 * 1024;          // [3072][1024]
    bf16* wpT = wT  + (size_t)3072 * 1024;          // [1024][1024]
    bf16* qw  = wpT + (size_t)1024 * 1024;          // [64 bh][1024 t][64 d]
    bf16* kw  = qw  + (size_t)64 * 1024 * 64;       // [64 bh][1024 t][64 d]
    bf16* vw  = kw  + (size_t)64 * 1024 * 64;       // [64 bh][64 d][1024 t']
    bf16* aw  = vw  + (size_t)64 * 1024 * 64;       // [4096][1024]

    conv_k<<<2048, 256, 0, stream>>>(x, xb, 4096 * 1024);
    transp_k<<<dim3(48, 16), 256, 0, stream>>>(w_attn, wT, 1024, 3072);
    transp_k<<<dim3(16, 16), 256, 0, stream>>>(w_proj, wpT, 1024, 1024);

    gemm_bt<0, 128><<<768, 256, 0, stream>>>(xb, wT, b_attn, qw, kw, vw,
                                             nullptr, 4096, 3072, 1024);
    attn_k<<<dim3(64, 8), 256, 0, stream>>>(qw, kw, vw, aw);
    gemm_bt<1, 64><<<512, 256, 0, stream>>>(aw, wpT, b_proj, nullptr, nullptr, nullptr,
                                            out, 4096, 1024, 1024);
}